// Round 9
// baseline (497.709 us; speedup 1.0000x reference)
//
#include <hip/hip_runtime.h>

#define DF 128

typedef __attribute__((ext_vector_type(8))) short bf16x8;
typedef __attribute__((ext_vector_type(4))) float f32x4;

__device__ __forceinline__ ushort f2bf(float f) {
  uint u = __float_as_uint(f);
  u += 0x7fff + ((u >> 16) & 1);
  return (ushort)(u >> 16);
}
__device__ __forceinline__ float bfl(uint v) { return __uint_as_float(v << 16); }
__device__ __forceinline__ float bfh(uint v) { return __uint_as_float(v & 0xffff0000u); }
__device__ __forceinline__ float b2f(ushort s) { return __uint_as_float(((uint)s) << 16); }

__device__ __forceinline__ void gload16(const ushort* g, ushort* l) {
  __builtin_amdgcn_global_load_lds((const __attribute__((address_space(1))) void*)g,
                                   (__attribute__((address_space(3))) void*)l, 16, 0, 0);
}

// ---------------- prepw: fragment-linear weights ----------------
// W1f[o]: o = ((k*32 + nt*4 + ks)*64 + lane)*8 + j  -> W1[k][kk][nn], nn=nt*16+(lane&15), kk=ks*32+(lane>>4)*8+j
// W2f[o]: o = ((nt*4 + ks)*64 + lane)*8 + j         -> W2[nt][kk][lane&15]
__global__ __launch_bounds__(256) void prepw_k(const float* __restrict__ W1, const float* __restrict__ W2,
                                               ushort* __restrict__ W1f, ushort* __restrict__ W2f) {
  int t = blockIdx.x * 256 + threadIdx.x;
  {
    int k = t >> 14, rem = t & 16383;
    int frag = rem >> 3, j = rem & 7;
    int nt = frag >> 8, ks = (frag >> 6) & 3, lane = frag & 63;
    int nn = nt * 16 + (lane & 15);
    int kk = ks * 32 + (lane >> 4) * 8 + j;
    W1f[t] = f2bf(W1[k * 16384 + kk * 128 + nn]);
  }
  if (t < 8192) {
    int frag = t >> 3, j = t & 7;
    int nt = frag >> 8, ks = (frag >> 6) & 3, lane = frag & 63;
    int kk = ks * 32 + (lane >> 4) * 8 + j;
    W2f[t] = f2bf(W2[nt * 2048 + kk * 16 + (lane & 15)]);
  }
}

// zero sentinel rows (row n of each 16-col slab / table)
__global__ void zero_k(ushort* BufA, ushort* Z3, ushort* GBs3, ushort* F0, ushort* F1, int n, int SL) {
  int tid = threadIdx.x;
  if (tid < 128) {
    int s = tid >> 4, c = tid & 15;
    BufA[(size_t)s * SL + (size_t)n * 16 + c] = 0;
    Z3[(size_t)s * SL + (size_t)n * 16 + c] = 0;
  }
  if (tid < 16) {
    GBs3[(size_t)n * 16 + tid] = 0;
    F0[(size_t)n * 16 + tid] = 0;
    F1[(size_t)n * 16 + tid] = 0;
  }
}

// ---------------- K1: gemmZ (blocks < GZ) | sharded deg hist + rank (rest) ----------------
// gemmZ: reads x f32, Z outputs RAW in sliced layout [slab=nt][node][16cols]
__global__ __launch_bounds__(256) void k1_k(const float* __restrict__ x, const ushort* __restrict__ W1f,
                                            ushort* __restrict__ Z3, ushort* __restrict__ Z2,
                                            ushort* __restrict__ Z1, ushort* __restrict__ Z0, int SL,
                                            const int* __restrict__ dst, int e,
                                            int* __restrict__ deg_s, int* __restrict__ rank,
                                            int n, int GZ) {
  __shared__ ushort wbuf[16384];   // 32 KB, single-buffered
  int b = blockIdx.x, tid = threadIdx.x;
  if (b >= GZ) {                   // hist part
    int i = (b - GZ) * 256 + tid;
    if (i < e) {
      int shard = (i >> 8) & 7;
      rank[i] = atomicAdd(&deg_s[(size_t)shard * n + dst[i]], 1);
    }
    return;
  }
  // gemmZ part
  int wid = tid >> 6, lane = tid & 63;
  int l15 = lane & 15, kgrp = lane >> 4;
  int m0 = b * 128 + wid * 32 + l15;
  int m1 = m0 + 16;
  int mc0 = m0 < n ? m0 : n - 1;
  int mc1 = m1 < n ? m1 : n - 1;
  bf16x8 xf0[4], xf1[4];
#pragma unroll
  for (int ks = 0; ks < 4; ks++) {
    float4 a0 = *reinterpret_cast<const float4*>(x + (size_t)mc0 * 128 + ks * 32 + kgrp * 8);
    float4 a1 = *reinterpret_cast<const float4*>(x + (size_t)mc0 * 128 + ks * 32 + kgrp * 8 + 4);
    float4 b0 = *reinterpret_cast<const float4*>(x + (size_t)mc1 * 128 + ks * 32 + kgrp * 8);
    float4 b1v = *reinterpret_cast<const float4*>(x + (size_t)mc1 * 128 + ks * 32 + kgrp * 8 + 4);
    bf16x8 u, w;
    u[0] = (short)f2bf(a0.x); u[1] = (short)f2bf(a0.y); u[2] = (short)f2bf(a0.z); u[3] = (short)f2bf(a0.w);
    u[4] = (short)f2bf(a1.x); u[5] = (short)f2bf(a1.y); u[6] = (short)f2bf(a1.z); u[7] = (short)f2bf(a1.w);
    w[0] = (short)f2bf(b0.x); w[1] = (short)f2bf(b0.y); w[2] = (short)f2bf(b0.z); w[3] = (short)f2bf(b0.w);
    w[4] = (short)f2bf(b1v.x); w[5] = (short)f2bf(b1v.y); w[6] = (short)f2bf(b1v.z); w[7] = (short)f2bf(b1v.w);
    xf0[ks] = u; xf1[ks] = w;
  }
#pragma unroll
  for (int kk = 0; kk < 4; kk++) {
    const int k = 3 - kk;
    {
      const ushort* gsrc = W1f + (size_t)k * 16384;
#pragma unroll
      for (int it = 0; it < 8; it++) {
        int f = it * 256 + tid;
        gload16(gsrc + (size_t)f * 8, &wbuf[f * 8]);
      }
    }
    __syncthreads();
    f32x4 acc0[8], acc1[8];
#pragma unroll
    for (int nt = 0; nt < 8; nt++) { acc0[nt] = {0.f,0.f,0.f,0.f}; acc1[nt] = {0.f,0.f,0.f,0.f}; }
#pragma unroll
    for (int ks = 0; ks < 4; ks++) {
#pragma unroll
      for (int nt = 0; nt < 8; nt++) {
        bf16x8 wf = *reinterpret_cast<const bf16x8*>(&wbuf[((nt * 4 + ks) * 64 + lane) * 8]);
        acc0[nt] = __builtin_amdgcn_mfma_f32_16x16x32_bf16(wf, xf0[ks], acc0[nt], 0, 0, 0);
        acc1[nt] = __builtin_amdgcn_mfma_f32_16x16x32_bf16(wf, xf1[ks], acc1[nt], 0, 0, 0);
      }
    }
    ushort* Out = (k == 3) ? Z3 : (k == 2) ? Z2 : (k == 1) ? Z1 : Z0;
#pragma unroll
    for (int nt = 0; nt < 8; nt++) {
      if (m0 < n) {
        ushort4 st; st.x = f2bf(acc0[nt][0]); st.y = f2bf(acc0[nt][1]);
        st.z = f2bf(acc0[nt][2]); st.w = f2bf(acc0[nt][3]);
        *reinterpret_cast<ushort4*>(Out + (size_t)nt * SL + (size_t)m0 * 16 + kgrp * 4) = st;
      }
      if (m1 < n) {
        ushort4 st; st.x = f2bf(acc1[nt][0]); st.y = f2bf(acc1[nt][1]);
        st.z = f2bf(acc1[nt][2]); st.w = f2bf(acc1[nt][3]);
        *reinterpret_cast<ushort4*>(Out + (size_t)nt * SL + (size_t)m1 * 16 + kgrp * 4) = st;
      }
    }
    __syncthreads();
  }
}

// fold shards: deg_total, per-shard exclusive prefix P, dis
__global__ __launch_bounds__(256) void reduce_k(const int* __restrict__ deg_s, int n,
                                                int* __restrict__ deg, int* __restrict__ P,
                                                float* __restrict__ dis) {
  int i = blockIdx.x * 256 + threadIdx.x;
  if (i >= n) return;
  int run = 0;
#pragma unroll
  for (int s = 0; s < 8; s++) {
    int v = deg_s[(size_t)s * n + i];
    P[(size_t)s * n + i] = run;
    run += v;
  }
  deg[i] = run;
  dis[i] = run > 0 ? rsqrtf((float)run) : 0.f;
}

// ---------------- exclusive scan (3-phase) ----------------
__global__ __launch_bounds__(256) void scan1_k(const int* __restrict__ deg, int n, int* __restrict__ partials) {
  __shared__ int sm[256];
  int base = blockIdx.x * 1024;
  int s = 0;
#pragma unroll
  for (int j = 0; j < 4; j++) { int idx = base + threadIdx.x * 4 + j; if (idx < n) s += deg[idx]; }
  sm[threadIdx.x] = s; __syncthreads();
  for (int off = 128; off > 0; off >>= 1) {
    if (threadIdx.x < off) sm[threadIdx.x] += sm[threadIdx.x + off];
    __syncthreads();
  }
  if (threadIdx.x == 0) partials[blockIdx.x] = sm[0];
}

__global__ void scan2_k(int* partials, int nb) {
  if (threadIdx.x == 0 && blockIdx.x == 0) {
    int run = 0;
    for (int i = 0; i < nb; i++) { int v = partials[i]; partials[i] = run; run += v; }
  }
}

__global__ __launch_bounds__(256) void scan3_k(const int* __restrict__ deg, int n, int e,
                                               const int* __restrict__ partials,
                                               int* __restrict__ rowptr) {
  __shared__ int sm[256];
  int base = blockIdx.x * 1024;
  int loc[4]; int s = 0;
#pragma unroll
  for (int j = 0; j < 4; j++) {
    int idx = base + threadIdx.x * 4 + j;
    int v = (idx < n) ? deg[idx] : 0;
    loc[j] = s; s += v;
  }
  sm[threadIdx.x] = s; __syncthreads();
  int tsum = s;
  for (int off = 1; off < 256; off <<= 1) {
    int v = (threadIdx.x >= (unsigned)off) ? sm[threadIdx.x - off] : 0;
    __syncthreads();
    sm[threadIdx.x] += v;
    __syncthreads();
  }
  int excl = sm[threadIdx.x] - tsum + partials[blockIdx.x];
#pragma unroll
  for (int j = 0; j < 4; j++) {
    int idx = base + threadIdx.x * 4 + j;
    if (idx < n) rowptr[idx] = excl + loc[j];
  }
  if (blockIdx.x == 0 && threadIdx.x == 0) rowptr[n] = e;
}

// ---------------- K2: csr_fill (blocks < gE) | in-place scale Z3 *= dis (rest) ----------------
__global__ __launch_bounds__(256) void k2_k(const int* __restrict__ src, const int* __restrict__ dst, int e,
                                            const int* __restrict__ rank, const int* __restrict__ rowptr,
                                            const int* __restrict__ P, int* __restrict__ colb,
                                            ushort* __restrict__ Z3, const float* __restrict__ dis,
                                            int n, int SL, int gE) {
  int b = blockIdx.x, tid = threadIdx.x;
  if (b < gE) {
    int i = b * 256 + tid;
    if (i < e) {
      int d = dst[i];
      int shard = (i >> 8) & 7;
      int p = rowptr[d] + P[(size_t)shard * n + d] + rank[i];
      colb[p] = src[i];
    }
  } else {
    int b2 = b - gE;
    int slab = b2 & 7;
    int u = (b2 >> 3) * 256 + tid;      // 0..2n-1: half-rows
    int i = u >> 1, gl = u & 1;
    if (i < n) {
      float d = dis[i];
      ushort* p = Z3 + (size_t)slab * SL + (size_t)i * 16 + gl * 8;
      uint4 v = *reinterpret_cast<const uint4*>(p);
      uint4 o;
      o.x = (uint)f2bf(d * bfl(v.x)) | ((uint)f2bf(d * bfh(v.x)) << 16);
      o.y = (uint)f2bf(d * bfl(v.y)) | ((uint)f2bf(d * bfh(v.y)) << 16);
      o.z = (uint)f2bf(d * bfl(v.z)) | ((uint)f2bf(d * bfh(v.z)) << 16);
      o.w = (uint)f2bf(d * bfl(v.w)) | ((uint)f2bf(d * bfh(v.w)) << 16);
      *reinterpret_cast<uint4*>(p) = o;
    }
  }
}

// ---------------- hop (XCD-sliced): t = dis_d * sum(hin'[src]) + zk[d]; slab = blockIdx&7 ----------------
__global__ __launch_bounds__(256) void hop_k(const ushort* __restrict__ hin, const ushort* __restrict__ zk,
                                             const float* __restrict__ b1, ushort* __restrict__ hout,
                                             const int* __restrict__ rowptr, const int* __restrict__ colb,
                                             const float* __restrict__ dis, int n, int SL, int last) {
  int slice = blockIdx.x & 7;
  int node = (blockIdx.x >> 3) * 128 + (threadIdx.x >> 1);
  int gl = threadIdx.x & 1;
  if (node >= n) return;
  const ushort* sin = hin + (size_t)slice * SL;
  int e0 = rowptr[node], e1 = rowptr[node + 1];
  float a0 = 0.f, a1 = 0.f, a2 = 0.f, a3 = 0.f, a4 = 0.f, a5 = 0.f, a6 = 0.f, a7 = 0.f;
  for (int ee = e0; ee < e1; ee += 8) {
    int c[8];
#pragma unroll
    for (int j = 0; j < 8; j++) {
      int idx = ee + j;
      c[j] = idx < e1 ? colb[idx] : n;     // row n is all-zero sentinel
    }
    uint4 v[8];
#pragma unroll
    for (int j = 0; j < 8; j++)
      v[j] = *reinterpret_cast<const uint4*>(sin + (size_t)c[j] * 16 + gl * 8);
#pragma unroll
    for (int j = 0; j < 8; j++) {
      a0 += bfl(v[j].x); a1 += bfh(v[j].x);
      a2 += bfl(v[j].y); a3 += bfh(v[j].y);
      a4 += bfl(v[j].z); a5 += bfh(v[j].z);
      a6 += bfl(v[j].w); a7 += bfh(v[j].w);
    }
  }
  float d = dis[node];
  uint4 zr = *reinterpret_cast<const uint4*>(zk + (size_t)slice * SL + (size_t)node * 16 + gl * 8);
  float t0 = fmaf(d, a0, bfl(zr.x)), t1 = fmaf(d, a1, bfh(zr.x));
  float t2 = fmaf(d, a2, bfl(zr.y)), t3 = fmaf(d, a3, bfh(zr.y));
  float t4 = fmaf(d, a4, bfl(zr.z)), t5 = fmaf(d, a5, bfh(zr.z));
  float t6 = fmaf(d, a6, bfl(zr.w)), t7 = fmaf(d, a7, bfh(zr.w));
  uint4 st;
  if (last) {
    int cb = slice * 16 + gl * 8;
    float4 bv0 = *reinterpret_cast<const float4*>(b1 + cb);
    float4 bv1 = *reinterpret_cast<const float4*>(b1 + cb + 4);
    t0 = fmaxf(t0 + bv0.x, 0.f); t1 = fmaxf(t1 + bv0.y, 0.f);
    t2 = fmaxf(t2 + bv0.z, 0.f); t3 = fmaxf(t3 + bv0.w, 0.f);
    t4 = fmaxf(t4 + bv1.x, 0.f); t5 = fmaxf(t5 + bv1.y, 0.f);
    t6 = fmaxf(t6 + bv1.z, 0.f); t7 = fmaxf(t7 + bv1.w, 0.f);
    st.x = (uint)f2bf(t0) | ((uint)f2bf(t1) << 16);
    st.y = (uint)f2bf(t2) | ((uint)f2bf(t3) << 16);
    st.z = (uint)f2bf(t4) | ((uint)f2bf(t5) << 16);
    st.w = (uint)f2bf(t6) | ((uint)f2bf(t7) << 16);
  } else {
    st.x = (uint)f2bf(d * t0) | ((uint)f2bf(d * t1) << 16);
    st.y = (uint)f2bf(d * t2) | ((uint)f2bf(d * t3) << 16);
    st.z = (uint)f2bf(d * t4) | ((uint)f2bf(d * t5) << 16);
    st.w = (uint)f2bf(d * t6) | ((uint)f2bf(d * t7) << 16);
  }
  *reinterpret_cast<uint4*>(hout + (size_t)slice * SL + (size_t)node * 16 + gl * 8) = st;
}

// ---------------- final GEMM: GB = h1 @ W2pack (raw) + GBs3 = dis * g3; h1 is sliced ----------------
__global__ __launch_bounds__(256) void gemm_last_k(const ushort* __restrict__ h1, const ushort* __restrict__ W2f,
                                                   const float* __restrict__ dis,
                                                   ushort* __restrict__ GB, ushort* __restrict__ GBs3,
                                                   int n, int SL) {
  int wid = threadIdx.x >> 6, lane = threadIdx.x & 63;
  int kgrp = lane >> 4;
  int m = blockIdx.x * 64 + wid * 16 + (lane & 15);
  int mc = m < n ? m : n - 1;
  float dm = dis[mc];
  bf16x8 xf[4];
#pragma unroll
  for (int ks = 0; ks < 4; ks++) {
    int slice = ks * 2 + (kgrp >> 1);
    xf[ks] = *reinterpret_cast<const bf16x8*>(h1 + (size_t)slice * SL + (size_t)mc * 16 + (kgrp & 1) * 8);
  }
#pragma unroll
  for (int nt = 0; nt < 4; nt++) {
    f32x4 acc = {0.f, 0.f, 0.f, 0.f};
#pragma unroll
    for (int ks = 0; ks < 4; ks++) {
      bf16x8 wf = *reinterpret_cast<const bf16x8*>(W2f + (size_t)((nt * 4 + ks) * 64 + lane) * 8);
      acc = __builtin_amdgcn_mfma_f32_16x16x32_bf16(wf, xf[ks], acc, 0, 0, 0);
    }
    if (m < n) {
      int ncol = nt * 16 + kgrp * 4;
      ushort4 st; st.x = f2bf(acc[0]); st.y = f2bf(acc[1]); st.z = f2bf(acc[2]); st.w = f2bf(acc[3]);
      *reinterpret_cast<ushort4*>(GB + (size_t)m * 64 + ncol) = st;
      if (nt == 3) {
        ushort4 ss; ss.x = f2bf(dm * acc[0]); ss.y = f2bf(dm * acc[1]);
        ss.z = f2bf(dm * acc[2]); ss.w = f2bf(dm * acc[3]);
        *reinterpret_cast<ushort4*>(GBs3 + (size_t)m * 16 + kgrp * 4) = ss;
      }
    }
  }
}

// ---------------- SpMM D=16: t = dis_d * sum(in'[src]) + add[d] ----------------
__global__ __launch_bounds__(256) void spmm16_k(const ushort* __restrict__ in,
                                                const ushort* __restrict__ addraw, int addstride,
                                                const float* __restrict__ b2,
                                                float* __restrict__ outf, ushort* __restrict__ outb,
                                                const int* __restrict__ rowptr, const int* __restrict__ colb,
                                                const float* __restrict__ dis, int n) {
  int t = blockIdx.x * 256 + threadIdx.x;
  int node = t >> 3, cp = t & 7;
  if (node >= n) return;
  int e0 = rowptr[node], e1 = rowptr[node + 1];
  float a0 = 0.f, a1 = 0.f;
  for (int ee = e0; ee < e1; ee += 4) {
    int c[4];
#pragma unroll
    for (int j = 0; j < 4; j++) {
      int idx = ee + j;
      c[j] = idx < e1 ? colb[idx] : n;
    }
    uint v[4];
#pragma unroll
    for (int j = 0; j < 4; j++)
      v[j] = *reinterpret_cast<const uint*>(in + (size_t)c[j] * 16 + cp * 2);
#pragma unroll
    for (int j = 0; j < 4; j++) { a0 += bfl(v[j]); a1 += bfh(v[j]); }
  }
  float d = dis[node];
  uint av = *reinterpret_cast<const uint*>(addraw + (size_t)node * addstride + cp * 2);
  float t0 = fmaf(d, a0, b2f((ushort)(av & 0xffff)));
  float t1 = fmaf(d, a1, b2f((ushort)(av >> 16)));
  if (outf) {
    float2 st; st.x = t0 + b2[cp * 2]; st.y = t1 + b2[cp * 2 + 1];
    *reinterpret_cast<float2*>(outf + (size_t)node * 16 + cp * 2) = st;
  } else {
    uint pk = (uint)f2bf(d * t0) | ((uint)f2bf(d * t1) << 16);
    *reinterpret_cast<uint*>(outb + (size_t)node * 16 + cp * 2) = pk;
  }
}

extern "C" void kernel_launch(void* const* d_in, const int* in_sizes, int n_in,
                              void* d_out, int out_size, void* d_ws, size_t ws_size,
                              hipStream_t stream) {
  const float* x  = (const float*)d_in[0];
  const int*   ei = (const int*)d_in[1];
  const float* W1 = (const float*)d_in[2];
  const float* b1 = (const float*)d_in[3];
  const float* W2 = (const float*)d_in[4];
  const float* b2 = (const float*)d_in[5];
  float* out = (float*)d_out;

  const int n = in_sizes[0] / DF;
  const int e = in_sizes[1] / 2;
  const int* srcp = ei;
  const int* dstp = ei + e;
  const int SL = (n + 1) * 16;     // slab stride (ushorts)

  char* ws = (char*)d_ws;
  size_t off = 0;
  auto alloc = [&](size_t bytes) -> void* {
    void* p = ws + off;
    off += (bytes + 255) & ~(size_t)255;
    return p;
  };
  ushort* BufA = (ushort*)alloc((size_t)8 * SL * 2);   // Tp (hop1 out), then h1 (hop3 out)
  ushort* Z3   = (ushort*)alloc((size_t)8 * SL * 2);   // z3 raw -> scaled in K2; then Up (hop2 out)
  ushort* Z2   = (ushort*)alloc((size_t)8 * SL * 2);   // later GB (n x 64)
  ushort* Z1   = (ushort*)alloc((size_t)8 * SL * 2);
  ushort* Z0   = (ushort*)alloc((size_t)8 * SL * 2);
  int*   deg_s = (int*)alloc((size_t)8 * n * 4);
  int*   P     = (int*)alloc((size_t)8 * n * 4);
  int*   deg   = (int*)alloc((size_t)n * 4);
  float* dis   = (float*)alloc((size_t)n * 4);
  int*   rowptr= (int*)alloc((size_t)(n + 1) * 4);
  int*   rank  = (int*)alloc((size_t)e * 4);
  int*   partials = (int*)alloc(1024 * 4);
  int*   colb  = (int*)alloc((size_t)e * 4);
  ushort* W1f  = (ushort*)alloc(4 * 128 * 128 * 2);
  ushort* W2f  = (ushort*)alloc(64 * 128 * 2);
  ushort* GBs3 = (ushort*)alloc((size_t)SL * 2);
  ushort* F0   = (ushort*)alloc((size_t)SL * 2);
  ushort* F1   = (ushort*)alloc((size_t)SL * 2);
  // aliases
  ushort* Tp = BufA;   // hop1 output (sliced, scaled)
  ushort* Up = Z3;     // hop2 output (sliced, scaled) — Z3 consumed by hop1
  ushort* h1 = BufA;   // hop3 output (sliced, raw) — Tp consumed by hop2
  ushort* GB = Z2;     // gemm_last output (row-major n x 64) — Z2 consumed by hop1's zk

  hipMemsetAsync(deg_s, 0, (size_t)8 * n * 4, stream);

  int gE = (e + 255) / 256;
  int gN = (n + 255) / 256;
  int nb = (n + 1023) / 1024;
  int GZ = (n + 127) / 128;

  zero_k<<<1, 256, 0, stream>>>(BufA, Z3, GBs3, F0, F1, n, SL);
  prepw_k<<<256, 256, 0, stream>>>(W1, W2, W1f, W2f);
  k1_k<<<GZ + gE, 256, 0, stream>>>(x, W1f, Z3, Z2, Z1, Z0, SL, dstp, e, deg_s, rank, n, GZ);
  reduce_k<<<gN, 256, 0, stream>>>(deg_s, n, deg, P, dis);
  scan1_k<<<nb, 256, 0, stream>>>(deg, n, partials);
  scan2_k<<<1, 64, 0, stream>>>(partials, nb);
  scan3_k<<<nb, 256, 0, stream>>>(deg, n, e, partials, rowptr);
  int gScale = 8 * ((2 * n + 255) / 256);
  k2_k<<<gE + gScale, 256, 0, stream>>>(srcp, dstp, e, rank, rowptr, P, colb, Z3, dis, n, SL, gE);

  int gHop = 8 * ((n + 127) / 128);
  int gGemm = (n + 63) / 64;
  int gS16 = (n * 8 + 255) / 256;

  // ----- Layer 1 Horner (sliced): p3=z3'; p2=A p3+z2; p1=A p2+z1; h1=relu(A p1+z0+b1)
  hop_k<<<gHop, 256, 0, stream>>>(Z3, Z2, nullptr, Tp, rowptr, colb, dis, n, SL, 0);
  hop_k<<<gHop, 256, 0, stream>>>(Tp, Z1, nullptr, Up, rowptr, colb, dis, n, SL, 0);
  hop_k<<<gHop, 256, 0, stream>>>(Up, Z0, b1, h1, rowptr, colb, dis, n, SL, 1);
  gemm_last_k<<<gGemm, 256, 0, stream>>>(h1, W2f, dis, GB, GBs3, n, SL);

  // ----- Layer 2 Horner at D=16: f2=A g3'+g2; f1=A f2'+g1; out=A f1'+g0+b2
  spmm16_k<<<gS16, 256, 0, stream>>>(GBs3, GB + 32, 64, nullptr, nullptr, F0, rowptr, colb, dis, n);
  spmm16_k<<<gS16, 256, 0, stream>>>(F0,   GB + 16, 64, nullptr, nullptr, F1, rowptr, colb, dis, n);
  spmm16_k<<<gS16, 256, 0, stream>>>(F1,   GB + 0,  64, b2, out, nullptr, rowptr, colb, dis, n);
}

// Round 10
// 406.531 us; speedup vs baseline: 1.2243x; 1.2243x over previous
//
#include <hip/hip_runtime.h>

#define DF 128

typedef __attribute__((ext_vector_type(8))) short bf16x8;
typedef __attribute__((ext_vector_type(4))) float f32x4;

__device__ __forceinline__ ushort f2bf(float f) {
  uint u = __float_as_uint(f);
  u += 0x7fff + ((u >> 16) & 1);
  return (ushort)(u >> 16);
}
__device__ __forceinline__ float bfl(uint v) { return __uint_as_float(v << 16); }
__device__ __forceinline__ float bfh(uint v) { return __uint_as_float(v & 0xffff0000u); }
__device__ __forceinline__ float b2f(ushort s) { return __uint_as_float(((uint)s) << 16); }

__device__ __forceinline__ void gload16(const ushort* g, ushort* l) {
  __builtin_amdgcn_global_load_lds((const __attribute__((address_space(1))) void*)g,
                                   (__attribute__((address_space(3))) void*)l, 16, 0, 0);
}

// ---------------- prepw (fragment-linear weights) + sentinel zeroing ----------------
// W1f[o]: o = ((k*32 + nt*4 + ks)*64 + lane)*8 + j  -> W1[k][kk][nn], nn=nt*16+(lane&15), kk=ks*32+(lane>>4)*8+j
// W2f[o]: o = ((nt*4 + ks)*64 + lane)*8 + j         -> W2[nt][kk][lane&15]
__global__ __launch_bounds__(256) void prepw_k(const float* __restrict__ W1, const float* __restrict__ W2,
                                               ushort* __restrict__ W1f, ushort* __restrict__ W2f,
                                               ushort* __restrict__ Z3s, ushort* __restrict__ T,
                                               ushort* __restrict__ GBs3, ushort* __restrict__ F0,
                                               ushort* __restrict__ F1, int n) {
  int b = blockIdx.x, tid = threadIdx.x;
  if (b == 256) {       // zero sentinel rows (row n)
    if (tid < 128) {
      Z3s[(size_t)n * 128 + tid] = 0;
      T[(size_t)n * 128 + tid] = 0;
    }
    if (tid < 16) {
      GBs3[(size_t)n * 16 + tid] = 0;
      F0[(size_t)n * 16 + tid] = 0;
      F1[(size_t)n * 16 + tid] = 0;
    }
    return;
  }
  int t = b * 256 + tid;
  {
    int k = t >> 14, rem = t & 16383;
    int frag = rem >> 3, j = rem & 7;
    int nt = frag >> 8, ks = (frag >> 6) & 3, lane = frag & 63;
    int nn = nt * 16 + (lane & 15);
    int kk = ks * 32 + (lane >> 4) * 8 + j;
    W1f[t] = f2bf(W1[k * 16384 + kk * 128 + nn]);
  }
  if (t < 8192) {
    int frag = t >> 3, j = t & 7;
    int nt = frag >> 8, ks = (frag >> 6) & 3, lane = frag & 63;
    int kk = ks * 32 + (lane >> 4) * 8 + j;
    W2f[t] = f2bf(W2[nt * 2048 + kk * 16 + (lane & 15)]);
  }
}

// ---------------- K1: gemmZ (blocks < GZ) | sharded deg hist + rank (rest) ----------------
// gemmZ reads x f32 directly; Z outputs row-major; z3 stored RAW (scaled later in k2)
__global__ __launch_bounds__(256) void k1_k(const float* __restrict__ x, const ushort* __restrict__ W1f,
                                            ushort* __restrict__ Z3, ushort* __restrict__ Z2,
                                            ushort* __restrict__ Z1, ushort* __restrict__ Z0,
                                            const int* __restrict__ dst, int e,
                                            int* __restrict__ deg_s, int* __restrict__ rank,
                                            int n, int GZ) {
  __shared__ ushort wbuf[16384];   // 32 KB, single-buffered
  int b = blockIdx.x, tid = threadIdx.x;
  if (b >= GZ) {                   // hist part
    int i = (b - GZ) * 256 + tid;
    if (i < e) {
      int shard = (i >> 8) & 7;
      rank[i] = atomicAdd(&deg_s[(size_t)shard * n + dst[i]], 1);
    }
    return;
  }
  // gemmZ part
  int wid = tid >> 6, lane = tid & 63;
  int l15 = lane & 15, kgrp = lane >> 4;
  int m0 = b * 128 + wid * 32 + l15;
  int m1 = m0 + 16;
  int mc0 = m0 < n ? m0 : n - 1;
  int mc1 = m1 < n ? m1 : n - 1;
  bf16x8 xf0[4], xf1[4];
#pragma unroll
  for (int ks = 0; ks < 4; ks++) {
    float4 a0 = *reinterpret_cast<const float4*>(x + (size_t)mc0 * 128 + ks * 32 + kgrp * 8);
    float4 a1 = *reinterpret_cast<const float4*>(x + (size_t)mc0 * 128 + ks * 32 + kgrp * 8 + 4);
    float4 b0 = *reinterpret_cast<const float4*>(x + (size_t)mc1 * 128 + ks * 32 + kgrp * 8);
    float4 b1v = *reinterpret_cast<const float4*>(x + (size_t)mc1 * 128 + ks * 32 + kgrp * 8 + 4);
    bf16x8 u, w;
    u[0] = (short)f2bf(a0.x); u[1] = (short)f2bf(a0.y); u[2] = (short)f2bf(a0.z); u[3] = (short)f2bf(a0.w);
    u[4] = (short)f2bf(a1.x); u[5] = (short)f2bf(a1.y); u[6] = (short)f2bf(a1.z); u[7] = (short)f2bf(a1.w);
    w[0] = (short)f2bf(b0.x); w[1] = (short)f2bf(b0.y); w[2] = (short)f2bf(b0.z); w[3] = (short)f2bf(b0.w);
    w[4] = (short)f2bf(b1v.x); w[5] = (short)f2bf(b1v.y); w[6] = (short)f2bf(b1v.z); w[7] = (short)f2bf(b1v.w);
    xf0[ks] = u; xf1[ks] = w;
  }
#pragma unroll
  for (int kk = 0; kk < 4; kk++) {
    const int k = 3 - kk;
    {
      const ushort* gsrc = W1f + (size_t)k * 16384;
#pragma unroll
      for (int it = 0; it < 8; it++) {
        int f = it * 256 + tid;
        gload16(gsrc + (size_t)f * 8, &wbuf[f * 8]);
      }
    }
    __syncthreads();
    f32x4 acc0[8], acc1[8];
#pragma unroll
    for (int nt = 0; nt < 8; nt++) { acc0[nt] = {0.f,0.f,0.f,0.f}; acc1[nt] = {0.f,0.f,0.f,0.f}; }
#pragma unroll
    for (int ks = 0; ks < 4; ks++) {
#pragma unroll
      for (int nt = 0; nt < 8; nt++) {
        bf16x8 wf = *reinterpret_cast<const bf16x8*>(&wbuf[((nt * 4 + ks) * 64 + lane) * 8]);
        acc0[nt] = __builtin_amdgcn_mfma_f32_16x16x32_bf16(wf, xf0[ks], acc0[nt], 0, 0, 0);
        acc1[nt] = __builtin_amdgcn_mfma_f32_16x16x32_bf16(wf, xf1[ks], acc1[nt], 0, 0, 0);
      }
    }
    ushort* Out = (k == 3) ? Z3 : (k == 2) ? Z2 : (k == 1) ? Z1 : Z0;
#pragma unroll
    for (int nt = 0; nt < 8; nt++) {
      int ncol = nt * 16 + kgrp * 4;
      if (m0 < n) {
        ushort4 st; st.x = f2bf(acc0[nt][0]); st.y = f2bf(acc0[nt][1]);
        st.z = f2bf(acc0[nt][2]); st.w = f2bf(acc0[nt][3]);
        *reinterpret_cast<ushort4*>(Out + (size_t)m0 * 128 + ncol) = st;
      }
      if (m1 < n) {
        ushort4 st; st.x = f2bf(acc1[nt][0]); st.y = f2bf(acc1[nt][1]);
        st.z = f2bf(acc1[nt][2]); st.w = f2bf(acc1[nt][3]);
        *reinterpret_cast<ushort4*>(Out + (size_t)m1 * 128 + ncol) = st;
      }
    }
    __syncthreads();
  }
}

// fold shards: deg_total, per-shard exclusive prefix P, dis
__global__ __launch_bounds__(256) void reduce_k(const int* __restrict__ deg_s, int n,
                                                int* __restrict__ deg, int* __restrict__ P,
                                                float* __restrict__ dis) {
  int i = blockIdx.x * 256 + threadIdx.x;
  if (i >= n) return;
  int run = 0;
#pragma unroll
  for (int s = 0; s < 8; s++) {
    int v = deg_s[(size_t)s * n + i];
    P[(size_t)s * n + i] = run;
    run += v;
  }
  deg[i] = run;
  dis[i] = run > 0 ? rsqrtf((float)run) : 0.f;
}

// ---------------- exclusive scan (3-phase) ----------------
__global__ __launch_bounds__(256) void scan1_k(const int* __restrict__ deg, int n, int* __restrict__ partials) {
  __shared__ int sm[256];
  int base = blockIdx.x * 1024;
  int s = 0;
#pragma unroll
  for (int j = 0; j < 4; j++) { int idx = base + threadIdx.x * 4 + j; if (idx < n) s += deg[idx]; }
  sm[threadIdx.x] = s; __syncthreads();
  for (int off = 128; off > 0; off >>= 1) {
    if (threadIdx.x < off) sm[threadIdx.x] += sm[threadIdx.x + off];
    __syncthreads();
  }
  if (threadIdx.x == 0) partials[blockIdx.x] = sm[0];
}

__global__ void scan2_k(int* partials, int nb) {
  if (threadIdx.x == 0 && blockIdx.x == 0) {
    int run = 0;
    for (int i = 0; i < nb; i++) { int v = partials[i]; partials[i] = run; run += v; }
  }
}

__global__ __launch_bounds__(256) void scan3_k(const int* __restrict__ deg, int n, int e,
                                               const int* __restrict__ partials,
                                               int* __restrict__ rowptr) {
  __shared__ int sm[256];
  int base = blockIdx.x * 1024;
  int loc[4]; int s = 0;
#pragma unroll
  for (int j = 0; j < 4; j++) {
    int idx = base + threadIdx.x * 4 + j;
    int v = (idx < n) ? deg[idx] : 0;
    loc[j] = s; s += v;
  }
  sm[threadIdx.x] = s; __syncthreads();
  int tsum = s;
  for (int off = 1; off < 256; off <<= 1) {
    int v = (threadIdx.x >= (unsigned)off) ? sm[threadIdx.x - off] : 0;
    __syncthreads();
    sm[threadIdx.x] += v;
    __syncthreads();
  }
  int excl = sm[threadIdx.x] - tsum + partials[blockIdx.x];
#pragma unroll
  for (int j = 0; j < 4; j++) {
    int idx = base + threadIdx.x * 4 + j;
    if (idx < n) rowptr[idx] = excl + loc[j];
  }
  if (blockIdx.x == 0 && threadIdx.x == 0) rowptr[n] = e;
}

// ---------------- K2: csr_fill (blocks < gE) | in-place scale Z3 *= dis (row-major) ----------------
__global__ __launch_bounds__(256) void k2_k(const int* __restrict__ src, const int* __restrict__ dst, int e,
                                            const int* __restrict__ rank, const int* __restrict__ rowptr,
                                            const int* __restrict__ P, int* __restrict__ colb,
                                            ushort* __restrict__ Z3, const float* __restrict__ dis,
                                            int n, int gE) {
  int b = blockIdx.x, tid = threadIdx.x;
  if (b < gE) {
    int i = b * 256 + tid;
    if (i < e) {
      int d = dst[i];
      int shard = (i >> 8) & 7;
      int p = rowptr[d] + P[(size_t)shard * n + d] + rank[i];
      colb[p] = src[i];
    }
  } else {
    int u = (b - gE) * 256 + tid;     // over n*16 8-col segments
    int i = u >> 4, seg = u & 15;
    if (i < n) {
      float d = dis[i];
      ushort* p = Z3 + (size_t)i * 128 + seg * 8;
      uint4 v = *reinterpret_cast<const uint4*>(p);
      uint4 o;
      o.x = (uint)f2bf(d * bfl(v.x)) | ((uint)f2bf(d * bfh(v.x)) << 16);
      o.y = (uint)f2bf(d * bfl(v.y)) | ((uint)f2bf(d * bfh(v.y)) << 16);
      o.z = (uint)f2bf(d * bfl(v.z)) | ((uint)f2bf(d * bfh(v.z)) << 16);
      o.w = (uint)f2bf(d * bfl(v.w)) | ((uint)f2bf(d * bfh(v.w)) << 16);
      *reinterpret_cast<uint4*>(p) = o;
    }
  }
}

// ---------------- hop: t = dis_d * sum(hin'[src]) + zk[d]; 16 lanes/node ----------------
__global__ __launch_bounds__(256) void hop_k(const ushort* __restrict__ hin, const ushort* __restrict__ zk,
                                             const float* __restrict__ b1, ushort* __restrict__ hout,
                                             const int* __restrict__ rowptr, const int* __restrict__ colb,
                                             const float* __restrict__ dis, int n, int last) {
  int node = blockIdx.x * 16 + (threadIdx.x >> 4);
  int gl = threadIdx.x & 15;
  if (node >= n) return;
  int e0 = rowptr[node], e1 = rowptr[node + 1];
  float a0 = 0.f, a1 = 0.f, a2 = 0.f, a3 = 0.f, a4 = 0.f, a5 = 0.f, a6 = 0.f, a7 = 0.f;
  for (int ee = e0; ee < e1; ee += 8) {
    int c[8];
#pragma unroll
    for (int j = 0; j < 8; j++) {
      int idx = ee + j;
      c[j] = idx < e1 ? colb[idx] : n;      // row n is all-zero sentinel
    }
    uint4 v[8];
#pragma unroll
    for (int j = 0; j < 8; j++)
      v[j] = *reinterpret_cast<const uint4*>(hin + (size_t)c[j] * 128 + gl * 8);
#pragma unroll
    for (int j = 0; j < 8; j++) {
      a0 += bfl(v[j].x); a1 += bfh(v[j].x);
      a2 += bfl(v[j].y); a3 += bfh(v[j].y);
      a4 += bfl(v[j].z); a5 += bfh(v[j].z);
      a6 += bfl(v[j].w); a7 += bfh(v[j].w);
    }
  }
  float d = dis[node];
  uint4 zr = *reinterpret_cast<const uint4*>(zk + (size_t)node * 128 + gl * 8);
  float t0 = fmaf(d, a0, bfl(zr.x)), t1 = fmaf(d, a1, bfh(zr.x));
  float t2 = fmaf(d, a2, bfl(zr.y)), t3 = fmaf(d, a3, bfh(zr.y));
  float t4 = fmaf(d, a4, bfl(zr.z)), t5 = fmaf(d, a5, bfh(zr.z));
  float t6 = fmaf(d, a6, bfl(zr.w)), t7 = fmaf(d, a7, bfh(zr.w));
  uint4 st;
  if (last) {
    float4 bv0 = *reinterpret_cast<const float4*>(b1 + gl * 8);
    float4 bv1 = *reinterpret_cast<const float4*>(b1 + gl * 8 + 4);
    t0 = fmaxf(t0 + bv0.x, 0.f); t1 = fmaxf(t1 + bv0.y, 0.f);
    t2 = fmaxf(t2 + bv0.z, 0.f); t3 = fmaxf(t3 + bv0.w, 0.f);
    t4 = fmaxf(t4 + bv1.x, 0.f); t5 = fmaxf(t5 + bv1.y, 0.f);
    t6 = fmaxf(t6 + bv1.z, 0.f); t7 = fmaxf(t7 + bv1.w, 0.f);
    st.x = (uint)f2bf(t0) | ((uint)f2bf(t1) << 16);
    st.y = (uint)f2bf(t2) | ((uint)f2bf(t3) << 16);
    st.z = (uint)f2bf(t4) | ((uint)f2bf(t5) << 16);
    st.w = (uint)f2bf(t6) | ((uint)f2bf(t7) << 16);
  } else {
    st.x = (uint)f2bf(d * t0) | ((uint)f2bf(d * t1) << 16);
    st.y = (uint)f2bf(d * t2) | ((uint)f2bf(d * t3) << 16);
    st.z = (uint)f2bf(d * t4) | ((uint)f2bf(d * t5) << 16);
    st.w = (uint)f2bf(d * t6) | ((uint)f2bf(d * t7) << 16);
  }
  *reinterpret_cast<uint4*>(hout + (size_t)node * 128 + gl * 8) = st;
}

// ---------------- final GEMM: GB = h1 @ W2pack (raw) + GBs3 = dis * g3 ----------------
__global__ __launch_bounds__(256) void gemm_last_k(const ushort* __restrict__ h1, const ushort* __restrict__ W2f,
                                                   const float* __restrict__ dis,
                                                   ushort* __restrict__ GB, ushort* __restrict__ GBs3, int n) {
  int wid = threadIdx.x >> 6, lane = threadIdx.x & 63;
  int kgrp = lane >> 4;
  int m = blockIdx.x * 64 + wid * 16 + (lane & 15);
  int mc = m < n ? m : n - 1;
  float dm = dis[mc];
  bf16x8 xf[4];
#pragma unroll
  for (int ks = 0; ks < 4; ks++)
    xf[ks] = *reinterpret_cast<const bf16x8*>(h1 + (size_t)mc * 128 + ks * 32 + kgrp * 8);
#pragma unroll
  for (int nt = 0; nt < 4; nt++) {
    f32x4 acc = {0.f, 0.f, 0.f, 0.f};
#pragma unroll
    for (int ks = 0; ks < 4; ks++) {
      bf16x8 wf = *reinterpret_cast<const bf16x8*>(W2f + (size_t)((nt * 4 + ks) * 64 + lane) * 8);
      acc = __builtin_amdgcn_mfma_f32_16x16x32_bf16(wf, xf[ks], acc, 0, 0, 0);
    }
    if (m < n) {
      int ncol = nt * 16 + kgrp * 4;
      ushort4 st; st.x = f2bf(acc[0]); st.y = f2bf(acc[1]); st.z = f2bf(acc[2]); st.w = f2bf(acc[3]);
      *reinterpret_cast<ushort4*>(GB + (size_t)m * 64 + ncol) = st;
      if (nt == 3) {
        ushort4 ss; ss.x = f2bf(dm * acc[0]); ss.y = f2bf(dm * acc[1]);
        ss.z = f2bf(dm * acc[2]); ss.w = f2bf(dm * acc[3]);
        *reinterpret_cast<ushort4*>(GBs3 + (size_t)m * 16 + kgrp * 4) = ss;
      }
    }
  }
}

// ---------------- SpMM D=16: t = dis_d * sum(in'[src]) + add[d] ----------------
__global__ __launch_bounds__(256) void spmm16_k(const ushort* __restrict__ in,
                                                const ushort* __restrict__ addraw, int addstride,
                                                const float* __restrict__ b2,
                                                float* __restrict__ outf, ushort* __restrict__ outb,
                                                const int* __restrict__ rowptr, const int* __restrict__ colb,
                                                const float* __restrict__ dis, int n) {
  int t = blockIdx.x * 256 + threadIdx.x;
  int node = t >> 3, cp = t & 7;
  if (node >= n) return;
  int e0 = rowptr[node], e1 = rowptr[node + 1];
  float a0 = 0.f, a1 = 0.f;
  for (int ee = e0; ee < e1; ee += 4) {
    int c[4];
#pragma unroll
    for (int j = 0; j < 4; j++) {
      int idx = ee + j;
      c[j] = idx < e1 ? colb[idx] : n;
    }
    uint v[4];
#pragma unroll
    for (int j = 0; j < 4; j++)
      v[j] = *reinterpret_cast<const uint*>(in + (size_t)c[j] * 16 + cp * 2);
#pragma unroll
    for (int j = 0; j < 4; j++) { a0 += bfl(v[j]); a1 += bfh(v[j]); }
  }
  float d = dis[node];
  uint av = *reinterpret_cast<const uint*>(addraw + (size_t)node * addstride + cp * 2);
  float t0 = fmaf(d, a0, b2f((ushort)(av & 0xffff)));
  float t1 = fmaf(d, a1, b2f((ushort)(av >> 16)));
  if (outf) {
    float2 st; st.x = t0 + b2[cp * 2]; st.y = t1 + b2[cp * 2 + 1];
    *reinterpret_cast<float2*>(outf + (size_t)node * 16 + cp * 2) = st;
  } else {
    uint pk = (uint)f2bf(d * t0) | ((uint)f2bf(d * t1) << 16);
    *reinterpret_cast<uint*>(outb + (size_t)node * 16 + cp * 2) = pk;
  }
}

extern "C" void kernel_launch(void* const* d_in, const int* in_sizes, int n_in,
                              void* d_out, int out_size, void* d_ws, size_t ws_size,
                              hipStream_t stream) {
  const float* x  = (const float*)d_in[0];
  const int*   ei = (const int*)d_in[1];
  const float* W1 = (const float*)d_in[2];
  const float* b1 = (const float*)d_in[3];
  const float* W2 = (const float*)d_in[4];
  const float* b2 = (const float*)d_in[5];
  float* out = (float*)d_out;

  const int n = in_sizes[0] / DF;
  const int e = in_sizes[1] / 2;
  const int* srcp = ei;
  const int* dstp = ei + e;

  char* ws = (char*)d_ws;
  size_t off = 0;
  auto alloc = [&](size_t bytes) -> void* {
    void* p = ws + off;
    off += (bytes + 255) & ~(size_t)255;
    return p;
  };
  ushort* Z3s  = (ushort*)alloc((size_t)(n + 1) * 128 * 2); // z3 (raw->scaled); then hop2 out
  ushort* T    = (ushort*)alloc((size_t)(n + 1) * 128 * 2); // hop1 out; then h1 (hop3 out)
  ushort* Z2   = (ushort*)alloc((size_t)n * 128 * 2);       // later GB (n x 64)
  ushort* Z1   = (ushort*)alloc((size_t)n * 128 * 2);
  ushort* Z0   = (ushort*)alloc((size_t)n * 128 * 2);
  int*   deg_s = (int*)alloc((size_t)8 * n * 4);
  int*   P     = (int*)alloc((size_t)8 * n * 4);
  int*   deg   = (int*)alloc((size_t)n * 4);
  float* dis   = (float*)alloc((size_t)n * 4);
  int*   rowptr= (int*)alloc((size_t)(n + 1) * 4);
  int*   rank  = (int*)alloc((size_t)e * 4);
  int*   partials = (int*)alloc(1024 * 4);
  int*   colb  = (int*)alloc((size_t)e * 4);
  ushort* W1f  = (ushort*)alloc(4 * 128 * 128 * 2);
  ushort* W2f  = (ushort*)alloc(64 * 128 * 2);
  ushort* GBs3 = (ushort*)alloc((size_t)(n + 1) * 16 * 2);
  ushort* F0   = (ushort*)alloc((size_t)(n + 1) * 16 * 2);
  ushort* F1   = (ushort*)alloc((size_t)(n + 1) * 16 * 2);
  // aliases
  ushort* Up = Z3s;   // hop2 output (Z3s consumed by hop1)
  ushort* h1 = T;     // hop3 output (T consumed by hop2)
  ushort* GB = Z2;    // gemm_last output (Z2 consumed by hop1's zk)

  hipMemsetAsync(deg_s, 0, (size_t)8 * n * 4, stream);

  int gE = (e + 255) / 256;
  int gN = (n + 255) / 256;
  int nb = (n + 1023) / 1024;
  int GZ = (n + 127) / 128;

  prepw_k<<<257, 256, 0, stream>>>(W1, W2, W1f, W2f, Z3s, T, GBs3, F0, F1, n);
  k1_k<<<GZ + gE, 256, 0, stream>>>(x, W1f, Z3s, Z2, Z1, Z0, dstp, e, deg_s, rank, n, GZ);
  reduce_k<<<gN, 256, 0, stream>>>(deg_s, n, deg, P, dis);
  scan1_k<<<nb, 256, 0, stream>>>(deg, n, partials);
  scan2_k<<<1, 64, 0, stream>>>(partials, nb);
  scan3_k<<<nb, 256, 0, stream>>>(deg, n, e, partials, rowptr);
  int gScale = (n * 16 + 255) / 256;
  k2_k<<<gE + gScale, 256, 0, stream>>>(srcp, dstp, e, rank, rowptr, P, colb, Z3s, dis, n, gE);

  int gHop = (n + 15) / 16;
  int gGemm = (n + 63) / 64;
  int gS16 = (n * 8 + 255) / 256;

  // ----- Layer 1 Horner: p3=z3'; p2=A p3+z2; p1=A p2+z1; h1=relu(A p1+z0+b1)
  hop_k<<<gHop, 256, 0, stream>>>(Z3s, Z2, nullptr, T, rowptr, colb, dis, n, 0);
  hop_k<<<gHop, 256, 0, stream>>>(T, Z1, nullptr, Up, rowptr, colb, dis, n, 0);
  hop_k<<<gHop, 256, 0, stream>>>(Up, Z0, b1, h1, rowptr, colb, dis, n, 1);
  gemm_last_k<<<gGemm, 256, 0, stream>>>(h1, W2f, dis, GB, GBs3, n);

  // ----- Layer 2 Horner at D=16: f2=A g3'+g2; f1=A f2'+g1; out=A f1'+g0+b2
  spmm16_k<<<gS16, 256, 0, stream>>>(GBs3, GB + 32, 64, nullptr, nullptr, F0, rowptr, colb, dis, n);
  spmm16_k<<<gS16, 256, 0, stream>>>(F0,   GB + 16, 64, nullptr, nullptr, F1, rowptr, colb, dis, n);
  spmm16_k<<<gS16, 256, 0, stream>>>(F1,   GB + 0,  64, b2, out, nullptr, rowptr, colb, dis, n);
}

// Round 11
// 404.653 us; speedup vs baseline: 1.2300x; 1.0046x over previous
//
#include <hip/hip_runtime.h>

#define DF 128

typedef __attribute__((ext_vector_type(8))) short bf16x8;
typedef __attribute__((ext_vector_type(4))) float f32x4;

__device__ __forceinline__ ushort f2bf(float f) {
  uint u = __float_as_uint(f);
  u += 0x7fff + ((u >> 16) & 1);
  return (ushort)(u >> 16);
}
__device__ __forceinline__ float bfl(uint v) { return __uint_as_float(v << 16); }
__device__ __forceinline__ float bfh(uint v) { return __uint_as_float(v & 0xffff0000u); }
__device__ __forceinline__ float b2f(ushort s) { return __uint_as_float(((uint)s) << 16); }

// ---------------- prepw (fragment-linear weights) + sentinel zeroing ----------------
// W1f[o]: o = ((k*32 + nt*4 + ks)*64 + lane)*8 + j  -> W1[k][kk][nn], nn=nt*16+(lane&15), kk=ks*32+(lane>>4)*8+j
// W2f[o]: o = ((nt*4 + ks)*64 + lane)*8 + j         -> W2[nt][kk][lane&15]
__global__ __launch_bounds__(256) void prepw_k(const float* __restrict__ W1, const float* __restrict__ W2,
                                               ushort* __restrict__ W1f, ushort* __restrict__ W2f,
                                               ushort* __restrict__ Z3s, ushort* __restrict__ T,
                                               ushort* __restrict__ GBs3, ushort* __restrict__ F0,
                                               ushort* __restrict__ F1, int n) {
  int b = blockIdx.x, tid = threadIdx.x;
  if (b == 256) {       // zero sentinel rows (row n)
    if (tid < 128) {
      Z3s[(size_t)n * 128 + tid] = 0;
      T[(size_t)n * 128 + tid] = 0;
    }
    if (tid < 16) {
      GBs3[(size_t)n * 16 + tid] = 0;
      F0[(size_t)n * 16 + tid] = 0;
      F1[(size_t)n * 16 + tid] = 0;
    }
    return;
  }
  int t = b * 256 + tid;
  {
    int k = t >> 14, rem = t & 16383;
    int frag = rem >> 3, j = rem & 7;
    int nt = frag >> 8, ks = (frag >> 6) & 3, lane = frag & 63;
    int nn = nt * 16 + (lane & 15);
    int kk = ks * 32 + (lane >> 4) * 8 + j;
    W1f[t] = f2bf(W1[k * 16384 + kk * 128 + nn]);
  }
  if (t < 8192) {
    int frag = t >> 3, j = t & 7;
    int nt = frag >> 8, ks = (frag >> 6) & 3, lane = frag & 63;
    int kk = ks * 32 + (lane >> 4) * 8 + j;
    W2f[t] = f2bf(W2[nt * 2048 + kk * 16 + (lane & 15)]);
  }
}

// ---------------- K1: gemmZ (blocks < GZ, no LDS, direct W frags) | sharded deg hist ----------------
__global__ __launch_bounds__(256) void k1_k(const float* __restrict__ x, const ushort* __restrict__ W1f,
                                            ushort* __restrict__ Z3, ushort* __restrict__ Z2,
                                            ushort* __restrict__ Z1, ushort* __restrict__ Z0,
                                            const int* __restrict__ dst, int e,
                                            int* __restrict__ deg_s, int* __restrict__ rank,
                                            int n, int GZ) {
  int b = blockIdx.x, tid = threadIdx.x;
  if (b >= GZ) {                   // hist part
    int i = (b - GZ) * 256 + tid;
    if (i < e) {
      int shard = (i >> 8) & 7;
      rank[i] = atomicAdd(&deg_s[(size_t)shard * n + dst[i]], 1);
    }
    return;
  }
  // gemmZ part: 2 row-fragments per wave, per-nt accumulators (low VGPR)
  int wid = tid >> 6, lane = tid & 63;
  int l15 = lane & 15, kgrp = lane >> 4;
  int m0 = b * 128 + wid * 32 + l15;
  int m1 = m0 + 16;
  int mc0 = m0 < n ? m0 : n - 1;
  int mc1 = m1 < n ? m1 : n - 1;
  bf16x8 xf0[4], xf1[4];
#pragma unroll
  for (int ks = 0; ks < 4; ks++) {
    float4 a0 = *reinterpret_cast<const float4*>(x + (size_t)mc0 * 128 + ks * 32 + kgrp * 8);
    float4 a1 = *reinterpret_cast<const float4*>(x + (size_t)mc0 * 128 + ks * 32 + kgrp * 8 + 4);
    float4 b0 = *reinterpret_cast<const float4*>(x + (size_t)mc1 * 128 + ks * 32 + kgrp * 8);
    float4 b1v = *reinterpret_cast<const float4*>(x + (size_t)mc1 * 128 + ks * 32 + kgrp * 8 + 4);
    bf16x8 u, w;
    u[0] = (short)f2bf(a0.x); u[1] = (short)f2bf(a0.y); u[2] = (short)f2bf(a0.z); u[3] = (short)f2bf(a0.w);
    u[4] = (short)f2bf(a1.x); u[5] = (short)f2bf(a1.y); u[6] = (short)f2bf(a1.z); u[7] = (short)f2bf(a1.w);
    w[0] = (short)f2bf(b0.x); w[1] = (short)f2bf(b0.y); w[2] = (short)f2bf(b0.z); w[3] = (short)f2bf(b0.w);
    w[4] = (short)f2bf(b1v.x); w[5] = (short)f2bf(b1v.y); w[6] = (short)f2bf(b1v.z); w[7] = (short)f2bf(b1v.w);
    xf0[ks] = u; xf1[ks] = w;
  }
#pragma unroll
  for (int kk = 0; kk < 4; kk++) {
    const int k = 3 - kk;
    const ushort* Wk = W1f + (size_t)k * 16384;
    ushort* Out = (k == 3) ? Z3 : (k == 2) ? Z2 : (k == 1) ? Z1 : Z0;
#pragma unroll
    for (int nt = 0; nt < 8; nt++) {
      f32x4 acc0 = {0.f, 0.f, 0.f, 0.f}, acc1 = {0.f, 0.f, 0.f, 0.f};
#pragma unroll
      for (int ks = 0; ks < 4; ks++) {
        bf16x8 wf = *reinterpret_cast<const bf16x8*>(Wk + (size_t)((nt * 4 + ks) * 64 + lane) * 8);
        acc0 = __builtin_amdgcn_mfma_f32_16x16x32_bf16(wf, xf0[ks], acc0, 0, 0, 0);
        acc1 = __builtin_amdgcn_mfma_f32_16x16x32_bf16(wf, xf1[ks], acc1, 0, 0, 0);
      }
      int ncol = nt * 16 + kgrp * 4;
      if (m0 < n) {
        ushort4 st; st.x = f2bf(acc0[0]); st.y = f2bf(acc0[1]);
        st.z = f2bf(acc0[2]); st.w = f2bf(acc0[3]);
        *reinterpret_cast<ushort4*>(Out + (size_t)m0 * 128 + ncol) = st;
      }
      if (m1 < n) {
        ushort4 st; st.x = f2bf(acc1[0]); st.y = f2bf(acc1[1]);
        st.z = f2bf(acc1[2]); st.w = f2bf(acc1[3]);
        *reinterpret_cast<ushort4*>(Out + (size_t)m1 * 128 + ncol) = st;
      }
    }
  }
}

// fold shards: deg_total, per-shard exclusive prefix P, dis
__global__ __launch_bounds__(256) void reduce_k(const int* __restrict__ deg_s, int n,
                                                int* __restrict__ deg, int* __restrict__ P,
                                                float* __restrict__ dis) {
  int i = blockIdx.x * 256 + threadIdx.x;
  if (i >= n) return;
  int run = 0;
#pragma unroll
  for (int s = 0; s < 8; s++) {
    int v = deg_s[(size_t)s * n + i];
    P[(size_t)s * n + i] = run;
    run += v;
  }
  deg[i] = run;
  dis[i] = run > 0 ? rsqrtf((float)run) : 0.f;
}

// ---------------- exclusive scan (3-phase) ----------------
__global__ __launch_bounds__(256) void scan1_k(const int* __restrict__ deg, int n, int* __restrict__ partials) {
  __shared__ int sm[256];
  int base = blockIdx.x * 1024;
  int s = 0;
#pragma unroll
  for (int j = 0; j < 4; j++) { int idx = base + threadIdx.x * 4 + j; if (idx < n) s += deg[idx]; }
  sm[threadIdx.x] = s; __syncthreads();
  for (int off = 128; off > 0; off >>= 1) {
    if (threadIdx.x < off) sm[threadIdx.x] += sm[threadIdx.x + off];
    __syncthreads();
  }
  if (threadIdx.x == 0) partials[blockIdx.x] = sm[0];
}

__global__ void scan2_k(int* partials, int nb) {
  if (threadIdx.x == 0 && blockIdx.x == 0) {
    int run = 0;
    for (int i = 0; i < nb; i++) { int v = partials[i]; partials[i] = run; run += v; }
  }
}

__global__ __launch_bounds__(256) void scan3_k(const int* __restrict__ deg, int n, int e,
                                               const int* __restrict__ partials,
                                               int* __restrict__ rowptr) {
  __shared__ int sm[256];
  int base = blockIdx.x * 1024;
  int loc[4]; int s = 0;
#pragma unroll
  for (int j = 0; j < 4; j++) {
    int idx = base + threadIdx.x * 4 + j;
    int v = (idx < n) ? deg[idx] : 0;
    loc[j] = s; s += v;
  }
  sm[threadIdx.x] = s; __syncthreads();
  int tsum = s;
  for (int off = 1; off < 256; off <<= 1) {
    int v = (threadIdx.x >= (unsigned)off) ? sm[threadIdx.x - off] : 0;
    __syncthreads();
    sm[threadIdx.x] += v;
    __syncthreads();
  }
  int excl = sm[threadIdx.x] - tsum + partials[blockIdx.x];
#pragma unroll
  for (int j = 0; j < 4; j++) {
    int idx = base + threadIdx.x * 4 + j;
    if (idx < n) rowptr[idx] = excl + loc[j];
  }
  if (blockIdx.x == 0 && threadIdx.x == 0) rowptr[n] = e;
}

// ---------------- K2: csr_fill (blocks < gE) | in-place scale Z3 *= dis ----------------
__global__ __launch_bounds__(256) void k2_k(const int* __restrict__ src, const int* __restrict__ dst, int e,
                                            const int* __restrict__ rank, const int* __restrict__ rowptr,
                                            const int* __restrict__ P, int* __restrict__ colb,
                                            ushort* __restrict__ Z3, const float* __restrict__ dis,
                                            int n, int gE) {
  int b = blockIdx.x, tid = threadIdx.x;
  if (b < gE) {
    int i = b * 256 + tid;
    if (i < e) {
      int d = dst[i];
      int shard = (i >> 8) & 7;
      int p = rowptr[d] + P[(size_t)shard * n + d] + rank[i];
      colb[p] = src[i];
    }
  } else {
    int u = (b - gE) * 256 + tid;     // over n*16 8-col segments
    int i = u >> 4, seg = u & 15;
    if (i < n) {
      float d = dis[i];
      ushort* p = Z3 + (size_t)i * 128 + seg * 8;
      uint4 v = *reinterpret_cast<const uint4*>(p);
      uint4 o;
      o.x = (uint)f2bf(d * bfl(v.x)) | ((uint)f2bf(d * bfh(v.x)) << 16);
      o.y = (uint)f2bf(d * bfl(v.y)) | ((uint)f2bf(d * bfh(v.y)) << 16);
      o.z = (uint)f2bf(d * bfl(v.z)) | ((uint)f2bf(d * bfh(v.z)) << 16);
      o.w = (uint)f2bf(d * bfl(v.w)) | ((uint)f2bf(d * bfh(v.w)) << 16);
      *reinterpret_cast<uint4*>(p) = o;
    }
  }
}

// ---------------- hop (half-column pass): t = dis_d * sum(hin'[src]) + zk[d] over 64 cols ----------------
// 16 lanes/node, 8B (uint2) per lane; colhalf selects cols [0,64) or [64,128)
__global__ __launch_bounds__(256) void hop_k(const ushort* __restrict__ hin, const ushort* __restrict__ zk,
                                             const float* __restrict__ b1, ushort* __restrict__ hout,
                                             const int* __restrict__ rowptr, const int* __restrict__ colb,
                                             const float* __restrict__ dis, int n, int colhalf, int last) {
  int node = blockIdx.x * 16 + (threadIdx.x >> 4);
  int gl = threadIdx.x & 15;
  if (node >= n) return;
  int cbase = colhalf * 64 + gl * 4;
  int e0 = rowptr[node], e1 = rowptr[node + 1];
  float a0 = 0.f, a1 = 0.f, a2 = 0.f, a3 = 0.f;
  for (int ee = e0; ee < e1; ee += 8) {
    int c[8];
#pragma unroll
    for (int j = 0; j < 8; j++) {
      int idx = ee + j;
      c[j] = idx < e1 ? colb[idx] : n;      // row n is all-zero sentinel
    }
    uint2 v[8];
#pragma unroll
    for (int j = 0; j < 8; j++)
      v[j] = *reinterpret_cast<const uint2*>(hin + (size_t)c[j] * 128 + cbase);
#pragma unroll
    for (int j = 0; j < 8; j++) {
      a0 += bfl(v[j].x); a1 += bfh(v[j].x);
      a2 += bfl(v[j].y); a3 += bfh(v[j].y);
    }
  }
  float d = dis[node];
  uint2 zr = *reinterpret_cast<const uint2*>(zk + (size_t)node * 128 + cbase);
  float t0 = fmaf(d, a0, bfl(zr.x)), t1 = fmaf(d, a1, bfh(zr.x));
  float t2 = fmaf(d, a2, bfl(zr.y)), t3 = fmaf(d, a3, bfh(zr.y));
  uint2 st;
  if (last) {
    float4 bv = *reinterpret_cast<const float4*>(b1 + cbase);
    t0 = fmaxf(t0 + bv.x, 0.f); t1 = fmaxf(t1 + bv.y, 0.f);
    t2 = fmaxf(t2 + bv.z, 0.f); t3 = fmaxf(t3 + bv.w, 0.f);
    st.x = (uint)f2bf(t0) | ((uint)f2bf(t1) << 16);
    st.y = (uint)f2bf(t2) | ((uint)f2bf(t3) << 16);
  } else {
    st.x = (uint)f2bf(d * t0) | ((uint)f2bf(d * t1) << 16);
    st.y = (uint)f2bf(d * t2) | ((uint)f2bf(d * t3) << 16);
  }
  *reinterpret_cast<uint2*>(hout + (size_t)node * 128 + cbase) = st;
}

// ---------------- final GEMM: GB = h1 @ W2pack (raw) + GBs3 = dis * g3 ----------------
__global__ __launch_bounds__(256) void gemm_last_k(const ushort* __restrict__ h1, const ushort* __restrict__ W2f,
                                                   const float* __restrict__ dis,
                                                   ushort* __restrict__ GB, ushort* __restrict__ GBs3, int n) {
  int wid = threadIdx.x >> 6, lane = threadIdx.x & 63;
  int kgrp = lane >> 4;
  int m = blockIdx.x * 64 + wid * 16 + (lane & 15);
  int mc = m < n ? m : n - 1;
  float dm = dis[mc];
  bf16x8 xf[4];
#pragma unroll
  for (int ks = 0; ks < 4; ks++)
    xf[ks] = *reinterpret_cast<const bf16x8*>(h1 + (size_t)mc * 128 + ks * 32 + kgrp * 8);
#pragma unroll
  for (int nt = 0; nt < 4; nt++) {
    f32x4 acc = {0.f, 0.f, 0.f, 0.f};
#pragma unroll
    for (int ks = 0; ks < 4; ks++) {
      bf16x8 wf = *reinterpret_cast<const bf16x8*>(W2f + (size_t)((nt * 4 + ks) * 64 + lane) * 8);
      acc = __builtin_amdgcn_mfma_f32_16x16x32_bf16(wf, xf[ks], acc, 0, 0, 0);
    }
    if (m < n) {
      int ncol = nt * 16 + kgrp * 4;
      ushort4 st; st.x = f2bf(acc[0]); st.y = f2bf(acc[1]); st.z = f2bf(acc[2]); st.w = f2bf(acc[3]);
      *reinterpret_cast<ushort4*>(GB + (size_t)m * 64 + ncol) = st;
      if (nt == 3) {
        ushort4 ss; ss.x = f2bf(dm * acc[0]); ss.y = f2bf(dm * acc[1]);
        ss.z = f2bf(dm * acc[2]); ss.w = f2bf(dm * acc[3]);
        *reinterpret_cast<ushort4*>(GBs3 + (size_t)m * 16 + kgrp * 4) = ss;
      }
    }
  }
}

// ---------------- SpMM D=16: t = dis_d * sum(in'[src]) + add[d] ----------------
__global__ __launch_bounds__(256) void spmm16_k(const ushort* __restrict__ in,
                                                const ushort* __restrict__ addraw, int addstride,
                                                const float* __restrict__ b2,
                                                float* __restrict__ outf, ushort* __restrict__ outb,
                                                const int* __restrict__ rowptr, const int* __restrict__ colb,
                                                const float* __restrict__ dis, int n) {
  int t = blockIdx.x * 256 + threadIdx.x;
  int node = t >> 3, cp = t & 7;
  if (node >= n) return;
  int e0 = rowptr[node], e1 = rowptr[node + 1];
  float a0 = 0.f, a1 = 0.f;
  for (int ee = e0; ee < e1; ee += 4) {
    int c[4];
#pragma unroll
    for (int j = 0; j < 4; j++) {
      int idx = ee + j;
      c[j] = idx < e1 ? colb[idx] : n;
    }
    uint v[4];
#pragma unroll
    for (int j = 0; j < 4; j++)
      v[j] = *reinterpret_cast<const uint*>(in + (size_t)c[j] * 16 + cp * 2);
#pragma unroll
    for (int j = 0; j < 4; j++) { a0 += bfl(v[j]); a1 += bfh(v[j]); }
  }
  float d = dis[node];
  uint av = *reinterpret_cast<const uint*>(addraw + (size_t)node * addstride + cp * 2);
  float t0 = fmaf(d, a0, b2f((ushort)(av & 0xffff)));
  float t1 = fmaf(d, a1, b2f((ushort)(av >> 16)));
  if (outf) {
    float2 st; st.x = t0 + b2[cp * 2]; st.y = t1 + b2[cp * 2 + 1];
    *reinterpret_cast<float2*>(outf + (size_t)node * 16 + cp * 2) = st;
  } else {
    uint pk = (uint)f2bf(d * t0) | ((uint)f2bf(d * t1) << 16);
    *reinterpret_cast<uint*>(outb + (size_t)node * 16 + cp * 2) = pk;
  }
}

extern "C" void kernel_launch(void* const* d_in, const int* in_sizes, int n_in,
                              void* d_out, int out_size, void* d_ws, size_t ws_size,
                              hipStream_t stream) {
  const float* x  = (const float*)d_in[0];
  const int*   ei = (const int*)d_in[1];
  const float* W1 = (const float*)d_in[2];
  const float* b1 = (const float*)d_in[3];
  const float* W2 = (const float*)d_in[4];
  const float* b2 = (const float*)d_in[5];
  float* out = (float*)d_out;

  const int n = in_sizes[0] / DF;
  const int e = in_sizes[1] / 2;
  const int* srcp = ei;
  const int* dstp = ei + e;

  char* ws = (char*)d_ws;
  size_t off = 0;
  auto alloc = [&](size_t bytes) -> void* {
    void* p = ws + off;
    off += (bytes + 255) & ~(size_t)255;
    return p;
  };
  ushort* Z3s  = (ushort*)alloc((size_t)(n + 1) * 128 * 2); // z3 (raw->scaled); then hop2 out
  ushort* T    = (ushort*)alloc((size_t)(n + 1) * 128 * 2); // hop1 out; then h1 (hop3 out)
  ushort* Z2   = (ushort*)alloc((size_t)n * 128 * 2);       // later GB (n x 64)
  ushort* Z1   = (ushort*)alloc((size_t)n * 128 * 2);
  ushort* Z0   = (ushort*)alloc((size_t)n * 128 * 2);
  int*   deg_s = (int*)alloc((size_t)8 * n * 4);
  int*   P     = (int*)alloc((size_t)8 * n * 4);
  int*   deg   = (int*)alloc((size_t)n * 4);
  float* dis   = (float*)alloc((size_t)n * 4);
  int*   rowptr= (int*)alloc((size_t)(n + 1) * 4);
  int*   rank  = (int*)alloc((size_t)e * 4);
  int*   partials = (int*)alloc(1024 * 4);
  int*   colb  = (int*)alloc((size_t)e * 4);
  ushort* W1f  = (ushort*)alloc(4 * 128 * 128 * 2);
  ushort* W2f  = (ushort*)alloc(64 * 128 * 2);
  ushort* GBs3 = (ushort*)alloc((size_t)(n + 1) * 16 * 2);
  ushort* F0   = (ushort*)alloc((size_t)(n + 1) * 16 * 2);
  ushort* F1   = (ushort*)alloc((size_t)(n + 1) * 16 * 2);
  // aliases
  ushort* Up = Z3s;   // hop2 output (Z3s consumed by hop1)
  ushort* h1 = T;     // hop3 output (T consumed by hop2)
  ushort* GB = Z2;    // gemm_last output (Z2 consumed by hop1's zk)

  hipMemsetAsync(deg_s, 0, (size_t)8 * n * 4, stream);

  int gE = (e + 255) / 256;
  int gN = (n + 255) / 256;
  int nb = (n + 1023) / 1024;
  int GZ = (n + 127) / 128;

  prepw_k<<<257, 256, 0, stream>>>(W1, W2, W1f, W2f, Z3s, T, GBs3, F0, F1, n);
  k1_k<<<GZ + gE, 256, 0, stream>>>(x, W1f, Z3s, Z2, Z1, Z0, dstp, e, deg_s, rank, n, GZ);
  reduce_k<<<gN, 256, 0, stream>>>(deg_s, n, deg, P, dis);
  scan1_k<<<nb, 256, 0, stream>>>(deg, n, partials);
  scan2_k<<<1, 64, 0, stream>>>(partials, nb);
  scan3_k<<<nb, 256, 0, stream>>>(deg, n, e, partials, rowptr);
  int gScale = (n * 16 + 255) / 256;
  k2_k<<<gE + gScale, 256, 0, stream>>>(srcp, dstp, e, rank, rowptr, P, colb, Z3s, dis, n, gE);

  int gHop = (n + 15) / 16;
  int gGemm = (n + 63) / 64;
  int gS16 = (n * 8 + 255) / 256;

  // ----- Layer 1 Horner (half-column hop passes): p3=z3'; p2=A p3+z2; p1=A p2+z1; h1=relu(A p1+z0+b1)
  hop_k<<<gHop, 256, 0, stream>>>(Z3s, Z2, nullptr, T, rowptr, colb, dis, n, 0, 0);
  hop_k<<<gHop, 256, 0, stream>>>(Z3s, Z2, nullptr, T, rowptr, colb, dis, n, 1, 0);
  hop_k<<<gHop, 256, 0, stream>>>(T, Z1, nullptr, Up, rowptr, colb, dis, n, 0, 0);
  hop_k<<<gHop, 256, 0, stream>>>(T, Z1, nullptr, Up, rowptr, colb, dis, n, 1, 0);
  hop_k<<<gHop, 256, 0, stream>>>(Up, Z0, b1, h1, rowptr, colb, dis, n, 0, 1);
  hop_k<<<gHop, 256, 0, stream>>>(Up, Z0, b1, h1, rowptr, colb, dis, n, 1, 1);
  gemm_last_k<<<gGemm, 256, 0, stream>>>(h1, W2f, dis, GB, GBs3, n);

  // ----- Layer 2 Horner at D=16: f2=A g3'+g2; f1=A f2'+g1; out=A f1'+g0+b2
  spmm16_k<<<gS16, 256, 0, stream>>>(GBs3, GB + 32, 64, nullptr, nullptr, F0, rowptr, colb, dis, n);
  spmm16_k<<<gS16, 256, 0, stream>>>(F0,   GB + 16, 64, nullptr, nullptr, F1, rowptr, colb, dis, n);
  spmm16_k<<<gS16, 256, 0, stream>>>(F1,   GB + 0,  64, b2, out, nullptr, rowptr, colb, dis, n);
}